// Round 6
// baseline (185.243 us; speedup 1.0000x reference)
//
#include <hip/hip_runtime.h>

// DWT2d db4 — write-stream-optimized: full-row tiles (TI=4 x 256), wave=subband,
// contiguous 4KB cached float4 store runs per wave (fillBuffer-like write path).
// Phase B: direct global float4 loads (proven neutral vs staging), row filter
// -> sm_lo/sm_hi. Phase C: wave w computes subband w for the whole tile and
// writes out[(bc*4+w)][it*4 .. it*4+3][0..255] = 4 x 1KB contiguous stores.
// x: (96, 512, 512) fp32 -> out: (96*4, 256, 256) fp32
// out[bc*4+s][i][j] = sum_{p,q} x[bc][(2i+p)%512][(2j+q)%512] * fH[s][p]*fW[s][q]

#define TI 4                // output rows per block
#define PR (2*TI + 6)       // 14 patch rows
#define HH 512
#define WW 512

__global__ __launch_bounds__(256)
void dwt2d_db4_kernel(const float* __restrict__ x,
                      const float* __restrict__ dec,
                      float* __restrict__ out) {
    __shared__ __align__(16) float sm_lo[PR][256];   // 14336 B
    __shared__ __align__(16) float sm_hi[PR][256];   // 14336 B -> 28672 B, 5 blocks/CU

    const int tid  = threadIdx.x;
    const int w    = tid >> 6;          // wave id = subband in phase C
    const int lane = tid & 63;

    // Block decode: XCD x (= n&7, hw round-robin) owns it-range [8x, 8x+8) for
    // every bc -> halo-sharing tiles hit its L2; within an XCD, consecutive
    // blocks advance it then bc -> per-XCD writes walk each plane sequentially.
    const int n   = blockIdx.x;
    const int x7  = n & 7;
    const int k   = n >> 3;
    const int it  = x7 * 8 + (k & 7);   // 0..63
    const int bc  = k >> 3;             // 0..95

    const int rowBase = it * (2 * TI);

    float flo[8], fhi[8];
#pragma unroll
    for (int q = 0; q < 8; ++q) { flo[q] = dec[q]; fhi[q] = dec[8 + q]; }

    const float* xb = x + (size_t)bc * HH * WW;

    // ---- Phase B: row pass, direct from global. Task (r,t) -> output pair
    //      (2t, 2t+1) of patch row r. Lane-consecutive t -> coalesced float4s. ----
    for (int task = tid; task < PR * 128; task += 256) {   // 1792 tasks, 7/thread
        int r = task >> 7;             // 0..13
        int t = task & 127;            // 0..127
        int gr = rowBase + r;          if (gr >= HH) gr -= HH;
        int c0 = 4 * t;                // 16B-aligned granule; wrap per granule
        int c1 = c0 + 4;               if (c1 >= WW) c1 -= WW;
        int c2 = c0 + 8;               if (c2 >= WW) c2 -= WW;
        const float* xr = xb + gr * WW;
        float4 v0 = *(const float4*)(xr + c0);
        float4 v1 = *(const float4*)(xr + c1);
        float4 v2 = *(const float4*)(xr + c2);
        float wv[12] = { v0.x, v0.y, v0.z, v0.w,
                         v1.x, v1.y, v1.z, v1.w,
                         v2.x, v2.y, v2.z, v2.w };
        float lo0 = 0.f, hi0 = 0.f, lo1 = 0.f, hi1 = 0.f;
#pragma unroll
        for (int q = 0; q < 8; ++q) {
            lo0 += wv[q]     * flo[q];
            hi0 += wv[q]     * fhi[q];
            lo1 += wv[q + 2] * flo[q];
            hi1 += wv[q + 2] * fhi[q];
        }
        *(float2*)&sm_lo[r][2 * t] = make_float2(lo0, lo1);
        *(float2*)&sm_hi[r][2 * t] = make_float2(hi0, hi1);
    }
    __syncthreads();

    // ---- Phase C: wave = subband. s: 0=LL(lo,flo) 1=LH(lo,fhi)
    //      2=HL(hi,flo) 3=HH(hi,fhi). Lane -> float4 of 4 consecutive j.
    //      One store instr = 64 lanes x 16B = 1KB contiguous; 4 instrs = 4KB run. ----
    {
        const float (*src)[256] = (w >= 2) ? sm_hi : sm_lo;
        const float* tap = (w & 1) ? fhi : flo;
        float* op = out + (((size_t)(bc * 4 + w) * 256 + (size_t)it * TI) * 256) + 4 * lane;
#pragma unroll
        for (int i = 0; i < TI; ++i) {
            float4 acc = make_float4(0.f, 0.f, 0.f, 0.f);
#pragma unroll
            for (int p = 0; p < 8; ++p) {
                float4 v = *(const float4*)&src[2 * i + p][4 * lane];
                float c = tap[p];
                acc.x += v.x * c; acc.y += v.y * c;
                acc.z += v.z * c; acc.w += v.w * c;
            }
            *(float4*)(op + (size_t)i * 256) = acc;   // cached store: L2 write-combining
        }
    }
}

extern "C" void kernel_launch(void* const* d_in, const int* in_sizes, int n_in,
                              void* d_out, int out_size, void* d_ws, size_t ws_size,
                              hipStream_t stream) {
    const float* x   = (const float*)d_in[0];
    const float* dec = (const float*)d_in[1];
    float* out = (float*)d_out;

    dim3 grid(8 * 8 * 96);               // 6144 blocks: (x7 | it-in-stripe | bc)
    dim3 block(256);
    dwt2d_db4_kernel<<<grid, block, 0, stream>>>(x, dec, out);
}